// Round 4
// baseline (169.584 us; speedup 1.0000x reference)
//
#include <hip/hip_runtime.h>
#include <hip/hip_fp16.h>

#define IN_F   4096
#define OUT_F  8192
#define M_ROWS 256

// R4: LDS-free, barrier-free structure. R1-R3 showed time pinned at ~50-55us
// across occupancy 19->50%, barrier-drain removal, and 2x M-tile: the
// barrier-phased LDS pipeline itself was the invariant limiter (pipes used
// serially in lockstep phases). Here each lane dequants exactly its own MFMA
// B-fragment (8 consecutive-k weights = one int2 + one norm) and loads its
// A-fragment from a fragment-ordered bf16 workspace (coalesced, L2-resident
// 2MB). No __shared__, no s_barrier anywhere in the K-loop; waves run free
// with depth-2 register pipelining.
#define SPLITK 4
#define K_SPL  (IN_F / SPLITK)     // 1024
#define NIT    (K_SPL / 32)        // 32 ksteps of K=32 per block
#define KS_TOT (IN_F / 32)         // 128 ksteps total

typedef __attribute__((ext_vector_type(8))) short  short8;   // 8 bf16
typedef __attribute__((ext_vector_type(4))) float  float4v;  // 4 fp32 acc

union pk8 { uint4 u; short8 s; };

// pack two fp32 into bf16x2 (truncation): [bf16(lo) | bf16(hi)<<16]
__device__ inline unsigned int pack_bf16(float lo, float hi) {
    return __builtin_amdgcn_perm(__float_as_uint(hi), __float_as_uint(lo), 0x07060302u);
}

// x fp32 -> bf16 workspace in FRAGMENT order: for (kstep ks, m-frag mf),
// a 1KB block of 64 lanes x 16B; lane (quad,l15) holds
// x[m = mf*16 + l15][k = ks*32 + quad*8 .. +7]. A-fragment loads in the gemm
// are then lane-linear (fully coalesced global_load_dwordx4).
__global__ void cvt_x_kernel(const float* __restrict__ x, uint4* __restrict__ xb) {
    const int tid = blockIdx.x * blockDim.x + threadIdx.x;
    if (tid >= (M_ROWS * IN_F) / 8) return;   // 131072 16B-chunks
    const int lane = tid & 63;
    const int mf   = (tid >> 6) & 15;
    const int ks   = tid >> 10;
    const int m    = mf * 16 + (lane & 15);
    const int k    = ks * 32 + (lane >> 4) * 8;
    const float* p = x + m * IN_F + k;
    float4 v0 = ((const float4*)p)[0], v1 = ((const float4*)p)[1];
    uint4 o;
    o.x = pack_bf16(v0.x, v0.y); o.y = pack_bf16(v0.z, v0.w);
    o.z = pack_bf16(v1.x, v1.y); o.w = pack_bf16(v1.z, v1.w);
    xb[tid] = o;
}

// out[m][n] = bias[n]  (split-K partials atomicAdd on top)
__global__ void init_out_kernel(const float* __restrict__ bias, float* __restrict__ out) {
    int i = blockIdx.x * blockDim.x + threadIdx.x;   // one float4 per thread
    if (i < (M_ROWS * OUT_F) / 4) {
        float4 b = ((const float4*)bias)[i & (OUT_F / 4 - 1)];
        ((float4*)out)[i] = b;
    }
}

// C[256,8192] += X * W^T (bias pre-written), fused 2-bit dequant of W.
// Block = 256 thr = 4 waves; each wave owns a 64m x 64n output tile
// (same m-range across the block's waves -> A fragments shared via L1/L2).
// Grid (N/256, M/64, SPLITK). Per wave per kstep(32): 4 A-frag loads
// (coalesced, L2-resident), 4 B-frags dequanted in-lane from wq, 16 MFMA.
template <bool XB>
__global__ __launch_bounds__(256, 1) void gemm2bit_kernel(
    const float* __restrict__ xf,     // used when !XB (fp32 x, frag-gathered)
    const uint4* __restrict__ xb,     // used when XB (frag-ordered bf16 ws)
    const int*   __restrict__ wq,     // int i holds weights 4i..4i+3 in bits 0,2,4,6
    const void*  __restrict__ wnorm,  // per-group-of-16 norm; fp32 or fp16, detected
    float*       __restrict__ out)
{
    const int t    = threadIdx.x;
    const int wave = t >> 6;
    const int lane = t & 63;
    const int l15  = lane & 15;
    const int quad = lane >> 4;

    const int nb   = blockIdx.x * 256 + wave * 64;   // wave's n base
    const int m0   = blockIdx.y * 64;                // block m base (shared)
    const int mb   = blockIdx.y * 4;                 // A m-frag base index
    const int ks0  = blockIdx.z * NIT;               // first kstep (absolute)

    // norm storage detection (valid norms in [1e-4, 0.0501]; fp16-pair
    // reinterpreted as fp32 is ~1e-13). Grid-uniform.
    const float cand0 = *(const float*)wnorm;
    const bool  nf32  = (cand0 > 1e-5f && cand0 < 0.1f);

    const char* wqB = (const char*)wq;
    const char* nmB = (const char*)wnorm;

    // Per-B-frag byte offsets (row part; add per-kstep term in the loop).
    // Weight k-range of lane's frag j: k = ks*32 + quad*8 .. +7
    //   -> wq int index n*1024 + ks*8 + quad*2 (verified bit-layout algebra)
    //   -> norm group    n*256  + ks*2 + (quad>>1)
    int qOff[4], nOff[4];
#pragma unroll
    for (int j = 0; j < 4; ++j) {
        const int n = nb + j * 16 + l15;
        qOff[j] = n * (IN_F / 4) * 4 + quad * 8;                       // bytes
        nOff[j] = nf32 ? (n * (IN_F / 16) * 4 + (quad >> 1) * 4)
                       : (n * (IN_F / 16) * 2 + (quad >> 1) * 2);      // bytes
    }

    float4v acc[4][4] = {};

    auto loadA = [&](uint4 (&a)[4], int ks) {
        if (XB) {
#pragma unroll
            for (int i = 0; i < 4; ++i)
                a[i] = xb[(ks * 16 + mb + i) * 64 + lane];
        } else {
#pragma unroll
            for (int i = 0; i < 4; ++i) {
                const float* p = xf + (m0 + i * 16 + l15) * IN_F + ks * 32 + quad * 8;
                float4 v0 = ((const float4*)p)[0], v1 = ((const float4*)p)[1];
                a[i].x = pack_bf16(v0.x, v0.y); a[i].y = pack_bf16(v0.z, v0.w);
                a[i].z = pack_bf16(v1.x, v1.y); a[i].w = pack_bf16(v1.z, v1.w);
            }
        }
    };

    auto loadB = [&](int2 (&q)[4], float (&nm)[4], int ks) {
#pragma unroll
        for (int j = 0; j < 4; ++j) {
            q[j]  = *(const int2*)(wqB + qOff[j] + ks * 32);
            nm[j] = nf32 ? *(const float*)(nmB + nOff[j] + ks * 8)
                         : __half2float(*(const __half*)(nmB + nOff[j] + ks * 4));
        }
    };

    auto process = [&](uint4 (&a)[4], int2 (&q)[4], float (&nm)[4]) {
#pragma unroll
        for (int j = 0; j < 4; ++j) {
            const float nC = nm[j];
            const float s  = nC * (2.0f / 3.0f);
            const int q0 = q[j].x, q1 = q[j].y;
            float f0 = fmaf((float)( q0       & 3), s, -nC);
            float f1 = fmaf((float)((q0 >> 2) & 3), s, -nC);
            float f2 = fmaf((float)((q0 >> 4) & 3), s, -nC);
            float f3 = fmaf((float)((q0 >> 6) & 3), s, -nC);
            float f4 = fmaf((float)( q1       & 3), s, -nC);
            float f5 = fmaf((float)((q1 >> 2) & 3), s, -nC);
            float f6 = fmaf((float)((q1 >> 4) & 3), s, -nC);
            float f7 = fmaf((float)((q1 >> 6) & 3), s, -nC);
            pk8 b;
            b.u.x = pack_bf16(f0, f1); b.u.y = pack_bf16(f2, f3);
            b.u.z = pack_bf16(f4, f5); b.u.w = pack_bf16(f6, f7);
#pragma unroll
            for (int i = 0; i < 4; ++i) {
                pk8 av; av.u = a[i];
                acc[i][j] = __builtin_amdgcn_mfma_f32_16x16x32_bf16(av.s, b.s, acc[i][j], 0, 0, 0);
            }
        }
    };

    // ---- depth-2 register pipeline, no barriers anywhere ----
    uint4 a0[4], a1[4]; int2 q0v[4], q1v[4]; float n0v[4], n1v[4];
    loadA(a0, ks0);     loadB(q0v, n0v, ks0);
    loadA(a1, ks0 + 1); loadB(q1v, n1v, ks0 + 1);

    for (int ito = 0; ito < NIT / 2; ++ito) {
        const int it = ks0 + ito * 2;
        process(a0, q0v, n0v);
        if (ito + 1 < NIT / 2) { loadA(a0, it + 2); loadB(q0v, n0v, it + 2); }
        process(a1, q1v, n1v);
        if (ito + 1 < NIT / 2) { loadA(a1, it + 3); loadB(q1v, n1v, it + 3); }
    }

    // ---- epilogue: atomic accumulate split-K partial ----
    // D[row=quad*4+r][col=lane&15] mapping (verified in prior rounds)
#pragma unroll
    for (int j = 0; j < 4; ++j) {
        const int col = nb + j * 16 + l15;
#pragma unroll
        for (int i = 0; i < 4; ++i) {
            const int row0 = m0 + i * 16 + quad * 4;
#pragma unroll
            for (int r = 0; r < 4; ++r)
                atomicAdd(&out[(row0 + r) * OUT_F + col], acc[i][j][r]);
        }
    }
}

extern "C" void kernel_launch(void* const* d_in, const int* in_sizes, int n_in,
                              void* d_out, int out_size, void* d_ws, size_t ws_size,
                              hipStream_t stream) {
    const float* x    = (const float*)d_in[0];
    const int*   wq   = (const int*)d_in[1];
    const void*  wn   = (const void*)d_in[2];
    const float* bias = (const float*)d_in[3];
    float*       out  = (float*)d_out;

    const bool use_ws = ws_size >= (size_t)(M_ROWS * IN_F * sizeof(unsigned short));

    dim3 grid(OUT_F / 256, M_ROWS / 64, SPLITK);  // 32 x 4 x 4 = 512 blocks

    // out = bias (broadcast rows); split-K partials land on top via atomicAdd
    init_out_kernel<<<dim3((M_ROWS * OUT_F / 4) / 256), 256, 0, stream>>>(bias, out);

    if (use_ws) {
        uint4* xbv = (uint4*)d_ws;
        cvt_x_kernel<<<dim3((M_ROWS * IN_F / 8) / 256), 256, 0, stream>>>(x, xbv);
        gemm2bit_kernel<true><<<grid, 256, 0, stream>>>(nullptr, xbv, wq, wn, out);
    } else {
        gemm2bit_kernel<false><<<grid, 256, 0, stream>>>(x, nullptr, wq, wn, out);
    }
}